// Round 1
// baseline (417.434 us; speedup 1.0000x reference)
//
#include <hip/hip_runtime.h>

// Problem constants (fixed in the reference file)
#define NCH   32
#define IH    64
#define IW    64
#define KH    5
#define KW    5
#define OHh   60
#define OWw   60
#define NBINS (OHh * OWw)   // 3600
#define NB    64            // batches
#define NS    4096          // spikes per batch
#define CAP   128

#define BLOCKS_PER_BATCH 15 // ceil(3600 / 256)

// One thread per (batch, output bin). Scan the batch's 4096 spikes in order;
// a spike v=(c,h,w) hits this bin iff kh=h-oh in [0,5) and kw=w-ow in [0,5).
// Append ckk = c*25 + kh*5 + kw at slot `count` (FCFS by s == reference's
// stable-sort rank). Spike value is wave-uniform -> scalar loads + SALU
// decompose; only the window compares are per-lane VALU.
__global__ __launch_bounds__(256) void sort_spikes_gather(
    const int* __restrict__ spikes, int* __restrict__ out) {
    const int b       = blockIdx.x / BLOCKS_PER_BATCH;
    const int binbase = (blockIdx.x % BLOCKS_PER_BATCH) * 256;
    const int bin     = binbase + (int)threadIdx.x;

    int oh, ow;
    if (bin < NBINS) {
        oh = bin / OWw;
        ow = bin - oh * OWw;
    } else {
        // Park inactive threads: window test can never pass.
        oh = -100000;
        ow = -100000;
    }

    const int* __restrict__ sp = spikes + b * NS;
    int* __restrict__ outcol = out + (size_t)b * CAP * NBINS + (bin < NBINS ? bin : 0);

    int count = 0;
    for (int s = 0; s < NS; s += 4) {
        // Wave-uniform address -> s_load_dwordx4 through the scalar path.
        const int4 v4 = *reinterpret_cast<const int4*>(sp + s);
#pragma unroll
        for (int k = 0; k < 4; ++k) {
            const int v = (k == 0) ? v4.x : (k == 1) ? v4.y : (k == 2) ? v4.z : v4.w;
            const int h = (v >> 6) & 63;   // SALU (v uniform)
            const int w = v & 63;          // SALU
            const unsigned kh = (unsigned)(h - oh);  // VALU
            const unsigned kw = (unsigned)(w - ow);  // VALU
            if ((kh < (unsigned)KH) & (kw < (unsigned)KW)) {   // rare (~0.6%/lane)
                if (count < CAP) {
                    const int ckk = (v >> 12) * (KH * KW) + (int)kh * KW + (int)kw;
                    outcol[count * NBINS] = ckk;
                }
                ++count;
            }
        }
    }
}

extern "C" void kernel_launch(void* const* d_in, const int* in_sizes, int n_in,
                              void* d_out, int out_size, void* d_ws, size_t ws_size,
                              hipStream_t stream) {
    const int* spikes = (const int*)d_in[0];  // (B, S, 1, 1) int32
    // d_in[1] (indices table) is unused: membership is pure arithmetic.
    int* out = (int*)d_out;                   // (B, CAP, OH, OW) int32

    // Fill output with -1 (0xFF bytes == int32 -1). Harness poisons d_out
    // with 0xAA before every timed call, so this must run every launch.
    hipMemsetAsync(out, 0xFF, (size_t)out_size * sizeof(int), stream);

    dim3 grid(NB * BLOCKS_PER_BATCH);
    dim3 block(256);
    sort_spikes_gather<<<grid, block, 0, stream>>>(spikes, out);
}

// Round 2
// 247.321 us; speedup vs baseline: 1.6878x; 1.6878x over previous
//
#include <hip/hip_runtime.h>

// Problem constants (fixed in the reference file)
#define OHh   60
#define OWw   60
#define NBINS (OHh * OWw)   // 3600
#define NB    64            // batches
#define NS    4096          // spikes per batch
#define CAP   128

// Tile: 16 ow x 4 oh bins per 64-thread (1-wave) block.
// Lanes 0-15 -> row oh0, lanes 16-31 -> oh0+1, etc. For a fixed slot the
// wave's stores form 4 x 64B segments (coalesced).
#define TOW 16
#define TOH 4
#define TILES_OW 4              // ceil(60/16) -> last tile has 4 parked cols
#define TILES_OH 15             // 60/4
#define TILES_PER_B (TILES_OW * TILES_OH)  // 60

// One wave per (batch, 16x4 bin tile). Scan the batch's spikes in 64-spike
// chunks; ballot-compact to spikes whose pixel lies in the tile's 20x8 halo
// (~3.9% hit rate), then broadcast each hit in s-order (ctz low->high) and do
// the per-bin 5x5 window test. FCFS order == reference's stable-sort rank.
__global__ __launch_bounds__(64) void sort_spikes_tile(
    const int* __restrict__ spikes, int* __restrict__ out) {
    const int tile = blockIdx.x % TILES_PER_B;
    const int b    = blockIdx.x / TILES_PER_B;
    const int oh0  = (tile / TILES_OW) * TOH;
    const int ow0  = (tile % TILES_OW) * TOW;
    const int lane = (int)threadIdx.x;

    const int oh = oh0 + (lane >> 4);
    const int ow = ow0 + (lane & 15);
    const bool valid_bin = (ow < OWw);      // oh always < 60 (15*4 == 60)
    const int bin = oh * OWw + ow;

    const int* __restrict__ sp = spikes + b * NS;
    int* __restrict__ outcol =
        out + (size_t)b * (CAP * NBINS) + (valid_bin ? bin : 0);

    int count = 0;
    int v = sp[lane];                       // prefetch chunk 0
    for (int c = 0; c < NS / 64; ++c) {
        int vn = 0;
        if (c + 1 < NS / 64) vn = sp[(c + 1) * 64 + lane];  // prefetch next

        const int h = (v >> 6) & 63;
        const int w = v & 63;
        // Spike relevant to tile iff pixel in [oh0, oh0+TOH+4) x [ow0, ow0+TOW+4)
        const bool halo = ((unsigned)(h - oh0) < (unsigned)(TOH + 4)) &
                          ((unsigned)(w - ow0) < (unsigned)(TOW + 4));
        unsigned long long mask = __ballot(halo);   // wave-uniform
        while (mask) {                               // uniform control flow
            const int j  = (int)__builtin_ctzll(mask);  // lowest lane = earliest s
            mask &= mask - 1;
            const int ju = __builtin_amdgcn_readfirstlane(j);
            const int vj = __builtin_amdgcn_readlane(v, ju);  // uniform spike
            const int hj = (vj >> 6) & 63;
            const int wj = vj & 63;
            const int cj = vj >> 12;
            const unsigned kh = (unsigned)(hj - oh);   // per-lane window test
            const unsigned kw = (unsigned)(wj - ow);
            const bool inwin = (kh < 5u) & (kw < 5u) & valid_bin;
            if (inwin && count < CAP)
                outcol[count * NBINS] = cj * 25 + (int)kh * 5 + (int)kw;
            count += inwin;
        }
        v = vn;
    }

    // Fill remaining slots with -1 (replaces the separate 118 MB memset).
    if (valid_bin) {
        for (int k = count; k < CAP; ++k)
            outcol[k * NBINS] = -1;
    }
}

extern "C" void kernel_launch(void* const* d_in, const int* in_sizes, int n_in,
                              void* d_out, int out_size, void* d_ws, size_t ws_size,
                              hipStream_t stream) {
    const int* spikes = (const int*)d_in[0];  // (B, S, 1, 1) int32
    // d_in[1] (indices table) unused: membership is pure arithmetic.
    int* out = (int*)d_out;                   // (B, CAP, OH, OW) int32

    dim3 grid(NB * TILES_PER_B);              // 3840 one-wave blocks
    dim3 block(64);
    sort_spikes_tile<<<grid, block, 0, stream>>>(spikes, out);
}

// Round 3
// 199.811 us; speedup vs baseline: 2.0891x; 1.2378x over previous
//
#include <hip/hip_runtime.h>

// Problem constants (fixed in the reference file)
#define OHh   60
#define OWw   60
#define NBINS (OHh * OWw)   // 3600
#define NB    64            // batches
#define NS    4096          // spikes per batch
#define CAP   128

// Tile: 16 ow x 4 oh bins per 64-thread (1-wave) block.
#define TOW 16
#define TOH 4
#define TILES_OW 4              // ceil(60/16) -> last tile column has 4 parked lanes
#define TILES_OH 15             // 60/4
#define TILES_PER_B (TILES_OW * TILES_OH)  // 60

// One wave per (batch, 16x4 bin tile). Scan spikes in 64-chunks, ballot-compact
// to the tile's 20x8 halo (~3.9% hit rate), broadcast hits in s-order (== the
// reference's stable-sort FCFS rank), append ckk into an LDS staging tile
// (int16, [slot][bin]), then dump the staged tile with dense 64B-aligned
// global stores. This removes the R2 bottleneck: sub-sector (20B) scattered
// global stores that caused 1.86x write amplification + RMW (219MB @ 1.5TB/s).
__global__ __launch_bounds__(64) void sort_spikes_tile(
    const int* __restrict__ spikes, int* __restrict__ out) {
    // Batch-minor block order: consecutive bids = different batches, so the
    // (typically round-robin) workgroup->XCD map pins batch b to XCD b%8 and
    // one L2 sees all of a batch's output lines (merges tile-boundary lines).
    const int bid  = (int)blockIdx.x;
    const int b    = bid & (NB - 1);
    const int tile = bid >> 6;
    const int oh0  = (tile / TILES_OW) * TOH;
    const int ow0  = (tile % TILES_OW) * TOW;
    const int lane = (int)threadIdx.x;

    const int oh = oh0 + (lane >> 4);
    const int ow = ow0 + (lane & 15);
    const bool valid_bin = (ow < OWw);      // oh always < 60

    // Staging tile: slot-major so lane (bin) is the contiguous axis.
    // ds_write_b16 at count*128 + lane*2: bank = (lane>>1)%32 independent of
    // count -> worst 2-way aliasing (free per m136). 16 KB -> 10 blocks/CU.
    __shared__ short stage[CAP][64];

    // Pre-fill with -1 (0xFFFF shorts): 16384 B = 1024 int4, 16 per lane.
    {
        int4* p = (int4*)&stage[0][0];
        const int4 m1 = make_int4(-1, -1, -1, -1);
#pragma unroll
        for (int i = 0; i < 16; ++i) p[i * 64 + lane] = m1;
    }
    __syncthreads();

    const int* __restrict__ sp = spikes + b * NS;

    int count = 0;
    int v = sp[lane];                       // prefetch chunk 0
    for (int c = 0; c < NS / 64; ++c) {
        int vn = 0;
        if (c + 1 < NS / 64) vn = sp[(c + 1) * 64 + lane];  // prefetch next

        const int h = (v >> 6) & 63;
        const int w = v & 63;
        // Relevant iff pixel in [oh0, oh0+TOH+4) x [ow0, ow0+TOW+4)
        const bool halo = ((unsigned)(h - oh0) < (unsigned)(TOH + 4)) &
                          ((unsigned)(w - ow0) < (unsigned)(TOW + 4));
        unsigned long long mask = __ballot(halo);   // wave-uniform
        while (mask) {                               // uniform control flow
            const int j  = (int)__builtin_ctzll(mask);  // lowest lane = earliest s
            mask &= mask - 1;
            const int ju = __builtin_amdgcn_readfirstlane(j);
            const int vj = __builtin_amdgcn_readlane(v, ju);  // uniform spike
            const int hj = (vj >> 6) & 63;
            const int wj = vj & 63;
            const int cj = vj >> 12;
            const unsigned kh = (unsigned)(hj - oh);   // per-lane window test
            const unsigned kw = (unsigned)(wj - ow);
            const bool inwin = (kh < 5u) & (kw < 5u);
            if (inwin && count < CAP)
                stage[count][lane] = (short)(cj * 25 + (int)kh * 5 + (int)kw);
            count += inwin;
        }
        v = vn;
    }
    __syncthreads();

    // Dense dump: per slot k, the wave writes 4 rows x 16 consecutive dwords
    // (64B-aligned full segments; every output byte written exactly once).
    if (valid_bin) {
        int* __restrict__ outp = out + (size_t)b * (CAP * NBINS) + oh * OWw + ow;
#pragma unroll 4
        for (int k = 0; k < CAP; ++k)
            outp[k * NBINS] = (int)stage[k][lane];   // sign-extends -1 / ckk
    }
}

extern "C" void kernel_launch(void* const* d_in, const int* in_sizes, int n_in,
                              void* d_out, int out_size, void* d_ws, size_t ws_size,
                              hipStream_t stream) {
    const int* spikes = (const int*)d_in[0];  // (B, S, 1, 1) int32
    // d_in[1] (indices table) unused: membership is pure arithmetic.
    int* out = (int*)d_out;                   // (B, CAP, OH, OW) int32

    dim3 grid(TILES_PER_B * NB);              // batch-minor: bid = tile*64 + b
    dim3 block(64);
    sort_spikes_tile<<<grid, block, 0, stream>>>(spikes, out);
}

// Round 4
// 191.538 us; speedup vs baseline: 2.1794x; 1.0432x over previous
//
#include <hip/hip_runtime.h>

// Problem constants (fixed in the reference file)
#define OHh   60
#define OWw   60
#define NBINS (OHh * OWw)   // 3600
#define NB    64            // batches
#define NS    4096          // spikes per batch
#define CAP   128
#define LSLOTS 64           // slots staged in LDS; >=LSLOTS handled directly

// One wave per (batch, output row). Lane == ow (lanes 60..63 parked).
//  - Scan spikes in 64-chunks; halo test is ONE compare: (unsigned)(h-row)<5
//    (kh is wave-uniform per broadcast spike; only kw is per-lane).
//  - Ballot-compact (~7.8% hit), broadcast hits in s-order (ctz low->high ==
//    reference's stable-sort FCFS rank), append ckk to LDS stage[slot][lane].
//  - Dump: per slot one contiguous 240 B run. Row pairs are 32 B-aligned and
//    the shared boundary sector is written by a block 64 bids away (same XCD,
//    batch-minor swizzle) -> merges in L2 -> ~zero sector amplification
//    (fixes R3's 1.34x WRITE_SIZE from 16-mod-32 row starts).
//  - Slots 64..127: almost always -1 (P(count>64) ~ 1e-10/bin); fill directly,
//    skipping k<count so the rare overflow path (direct global store during
//    scan) is never overwritten. 8 KB LDS -> 20 blocks/CU (62% occupancy cap
//    vs R3's 31%).
__global__ __launch_bounds__(64) void sort_spikes_row(
    const int* __restrict__ spikes, int* __restrict__ out) {
    const int bid  = (int)blockIdx.x;
    const int b    = bid & (NB - 1);   // batch-minor -> batch b on XCD b%8
    const int row  = bid >> 6;         // output row oh, 0..59
    const int lane = (int)threadIdx.x; // == ow; lanes 60..63 parked
    const bool valid = lane < OWw;

    __shared__ short stage[LSLOTS][64];   // 8192 B

    // Prefill -1 (0xFFFF): 512 int4 -> 8 per lane.
    {
        int4* p = (int4*)&stage[0][0];
        const int4 m1 = make_int4(-1, -1, -1, -1);
#pragma unroll
        for (int i = 0; i < 8; ++i) p[i * 64 + lane] = m1;
    }
    __syncthreads();   // 1 wave: compiles to lgkmcnt wait, essentially free

    const int* __restrict__ sp = spikes + b * NS;
    int* __restrict__ outb = out + (size_t)b * (CAP * NBINS) + row * OWw;

    int count = 0;
    int v = sp[lane];                          // prefetch chunk 0
    for (int c = 0; c < NS / 64; ++c) {
        int vn = 0;
        if (c + 1 < NS / 64) vn = sp[(c + 1) * 64 + lane];  // prefetch next

        const int h = (v >> 6) & 63;
        const bool halo = (unsigned)(h - row) < 5u;   // full-row tile: w always in range
        unsigned long long mask = __ballot(halo);     // wave-uniform
        while (mask) {                                 // uniform control flow
            const int j = (int)__builtin_ctzll(mask);  // lowest lane = earliest s
            mask &= mask - 1;
            const int vj =
                __builtin_amdgcn_readlane(v, __builtin_amdgcn_readfirstlane(j));
            const int wj  = vj & 63;                    // scalar
            const int khj = ((vj >> 6) & 63) - row;     // scalar, in [0,5)
            const int cj  = vj >> 12;                   // scalar
            const int kw  = wj - lane;                  // per-lane
            const bool act = ((unsigned)kw < 5u) & valid;  // <=5 lanes active
            if (act) {
                const int ckk = cj * 25 + khj * 5 + kw;
                if (count < LSLOTS)
                    stage[count][lane] = (short)ckk;
                else if (count < CAP)
                    outb[count * NBINS + lane] = ckk;   // freak overflow path
                ++count;
            }
        }
        v = vn;
    }
    __syncthreads();

    if (valid) {
        // Slots 0..63 from LDS: per slot a contiguous 240 B wave store.
        // ds_read_u16 banks = lane>>1 (2-way, free).
#pragma unroll 4
        for (int k = 0; k < LSLOTS; ++k)
            outb[k * NBINS + lane] = (int)stage[k][lane];
        // Slots 64..127: -1 fill, skipping slots the overflow path wrote.
        for (int k = LSLOTS; k < CAP; ++k)
            if (k >= count) outb[k * NBINS + lane] = -1;
    }
}

extern "C" void kernel_launch(void* const* d_in, const int* in_sizes, int n_in,
                              void* d_out, int out_size, void* d_ws, size_t ws_size,
                              hipStream_t stream) {
    const int* spikes = (const int*)d_in[0];  // (B, S, 1, 1) int32
    // d_in[1] (indices table) unused: membership is pure arithmetic.
    int* out = (int*)d_out;                   // (B, CAP, OH, OW) int32

    dim3 grid(OHh * NB);                      // 3840 one-wave blocks, batch-minor
    dim3 block(64);
    sort_spikes_row<<<grid, block, 0, stream>>>(spikes, out);
}

// Round 5
// 164.905 us; speedup vs baseline: 2.5314x; 1.1615x over previous
//
#include <hip/hip_runtime.h>

// Problem constants (fixed in the reference file)
#define OHh   60
#define OWw   60
#define NBINS (OHh * OWw)   // 3600
#define NB    64            // batches
#define NS    4096          // spikes per batch
#define CAP   128

#define NW     4            // waves per block
#define SEG    (NS / NW)    // 1024 spikes scanned per wave
#define CH     (SEG / 64)   // 16 chunks per wave
#define WSLOTS 48           // staged slots per wave-segment per bin

// One 4-wave block per (batch, output row). Lane == ow (lanes 60..63 parked).
// Wave w scans spike segment [w*1024,(w+1)*1024): halo test is ONE compare
// ((unsigned)(h-row)<5; kh wave-uniform, only kw per-lane). Ballot-compact
// (~7.8% hit), broadcast hits in s-order (ctz low->high), stage ckk in LDS
// stage[w][slot][lane]. Dump: concatenate segments in wave order (== s-order
// == reference's stable-sort FCFS rank); each wave writes 32 output slots as
// contiguous 240 B runs (R4's write-efficient pattern, WRITE_SIZE ~= output).
// vs R4: serial chain per wave /4, 4x waves for latency hiding, all 16 chunk
// loads issued up-front (one L2 latency instead of 64).
__global__ __launch_bounds__(256) void sort_spikes_row4(
    const int* __restrict__ spikes, int* __restrict__ out) {
    const int bid  = (int)blockIdx.x;
    const int b    = bid & (NB - 1);   // batch-minor -> batch b pinned to XCD b%8
    const int row  = bid >> 6;         // output row oh, 0..59
    const int tid  = (int)threadIdx.x;
    const int wv   = tid >> 6;
    const int lane = tid & 63;
    const bool valid = lane < OWw;

    __shared__ short stage[NW][WSLOTS][64];  // 24576 B; slot stride 128 B -> bank = lane>>1 (2-way, free)
    __shared__ int   cnt[NW][64];            // per-segment per-bin hit counts
    __shared__ int   ovf;                    // staging-overflow flag (never in practice)

    if (tid == 0) ovf = 0;

    const int* __restrict__ sp   = spikes + b * NS + wv * SEG;
    int* __restrict__       outb = out + (size_t)b * (CAP * NBINS) + row * OWw;

    // Issue all 16 chunk loads up front (deep vmcnt pipeline; L2-resident
    // after the first of a batch's 60 blocks touches them).
    int vs[CH];
#pragma unroll
    for (int c = 0; c < CH; ++c) vs[c] = sp[c * 64 + lane];

    int count = 0;
#pragma unroll
    for (int c = 0; c < CH; ++c) {
        const int v = vs[c];
        const int h = (v >> 6) & 63;
        unsigned long long mask = __ballot((unsigned)(h - row) < 5u);  // wave-uniform
        while (mask) {                                 // uniform control flow
            const int j = (int)__builtin_ctzll(mask);  // lowest lane = earliest s
            mask &= mask - 1;
            const int vj =
                __builtin_amdgcn_readlane(v, __builtin_amdgcn_readfirstlane(j));
            const int wj  = vj & 63;                   // scalar
            const int khj = ((vj >> 6) & 63) - row;    // scalar, in [0,5)
            const int cj  = vj >> 12;                  // scalar
            const int kw  = wj - lane;                 // per-lane
            if (((unsigned)kw < 5u) & valid) {         // <=5 lanes active
                if (count < WSLOTS)
                    stage[wv][count][lane] = (short)(cj * 25 + khj * 5 + kw);
                ++count;
            }
        }
    }
    cnt[wv][lane] = count;
    if (__ballot(count > WSLOTS) && lane == 0) ovf = 1;  // benign multi-write of 1
    __syncthreads();

    if (ovf == 0) {
        if (valid) {
            const int c0 = cnt[0][lane], c1 = cnt[1][lane];
            const int c2 = cnt[2][lane], c3 = cnt[3][lane];
            const int o1 = c0, o2 = c0 + c1, o3 = o2 + c2;
            const int total = o3 + c3;                 // <= 192, write only k<128
#pragma unroll 4
            for (int i = 0; i < CAP / NW; ++i) {
                const int k = wv * (CAP / NW) + i;     // wave order == s order
                int val = -1;
                if (k < total) {
                    int wsel = 0, base = 0;
                    if (k >= o1) { wsel = 1; base = o1; }
                    if (k >= o2) { wsel = 2; base = o2; }
                    if (k >= o3) { wsel = 3; base = o3; }
                    val = (int)stage[wsel][k - base][lane];  // bank = lane>>1, free
                }
                outb[k * NBINS + lane] = val;          // contiguous 240 B run
            }
        }
    } else if (wv == 0) {
        // Fallback: a 1024-spike segment put >48 hits in one bin
        // (P ~ 1e-19 for random input). Wave 0 redoes the row serially
        // with direct global stores. Correct, slow, never taken.
        const int* __restrict__ spf = spikes + b * NS;
        int cc = 0;
        for (int c = 0; c < NS / 64; ++c) {
            const int v = spf[c * 64 + lane];
            const int h = (v >> 6) & 63;
            unsigned long long mask = __ballot((unsigned)(h - row) < 5u);
            while (mask) {
                const int j = (int)__builtin_ctzll(mask);
                mask &= mask - 1;
                const int vj =
                    __builtin_amdgcn_readlane(v, __builtin_amdgcn_readfirstlane(j));
                const int wj  = vj & 63;
                const int khj = ((vj >> 6) & 63) - row;
                const int cj  = vj >> 12;
                const int kw  = wj - lane;
                if (((unsigned)kw < 5u) & valid) {
                    if (cc < CAP)
                        outb[cc * NBINS + lane] = cj * 25 + khj * 5 + kw;
                    ++cc;
                }
            }
        }
        if (valid)
            for (int k = cc; k < CAP; ++k) outb[k * NBINS + lane] = -1;
    }
}

extern "C" void kernel_launch(void* const* d_in, const int* in_sizes, int n_in,
                              void* d_out, int out_size, void* d_ws, size_t ws_size,
                              hipStream_t stream) {
    const int* spikes = (const int*)d_in[0];  // (B, S, 1, 1) int32
    // d_in[1] (indices table) unused: membership is pure arithmetic.
    int* out = (int*)d_out;                   // (B, CAP, OH, OW) int32

    dim3 grid(OHh * NB);                      // 3840 blocks, batch-minor
    dim3 block(256);                          // 4 waves/block
    sort_spikes_row4<<<grid, block, 0, stream>>>(spikes, out);
}

// Round 6
// 149.751 us; speedup vs baseline: 2.7875x; 1.1012x over previous
//
#include <hip/hip_runtime.h>

// Problem constants (fixed in the reference file)
#define OHh   60
#define OWw   60
#define NBINS (OHh * OWw)   // 3600
#define NB    64            // batches
#define NS    4096          // spikes per batch
#define CAP   128

#define NW     4            // waves per block
#define SEG    (NS / NW)    // 1024 spikes scanned per wave
#define CH     (SEG / 64)   // 16 chunks per wave
#define WSLOTS 48           // staged slots per wave-segment per bin (+1 dummy row)

// One 4-wave block per (batch, output row); lane == ow (lanes 60..63 parked).
// R5 was scalar-unit-bound: ~15 SALU per broadcast-hit x 1.31M hits / 256 CUs
// ~= 32 us on the one shared SALU per CU. R6 strips the hit loop:
//  - payload P = ((c*25 + (h-row)*5)<<6) | w pre-packed per chunk on VALU
//    (parallel, ~6 VALU/chunk) -> per hit the scalar side is just
//    s_ff1 + mask clear + readlane + 2 extracts + branch.
//  - LDS write made branchless: address cndmask'd to a dummy row instead of
//    exec save/restore.
// Dump unchanged from R4/R5 (WRITE_SIZE == output size, ~1.0x amplification).
__global__ __launch_bounds__(256) void sort_spikes_row4(
    const int* __restrict__ spikes, int* __restrict__ out) {
    const int bid  = (int)blockIdx.x;
    const int b    = bid & (NB - 1);   // batch-minor -> batch b pinned to XCD b%8
    const int row  = bid >> 6;         // output row oh, 0..59
    const int tid  = (int)threadIdx.x;
    const int wv   = tid >> 6;
    const int lane = tid & 63;
    const bool valid = lane < OWw;

    // [WSLOTS] real slots + 1 dummy row (branchless-write sink).
    __shared__ short stage[NW][WSLOTS + 1][64];  // 25088 B
    __shared__ int   cnt[NW][64];
    __shared__ int   ovf;

    if (tid == 0) ovf = 0;

    const int* __restrict__ sp   = spikes + b * NS + wv * SEG;
    int* __restrict__       outb = out + (size_t)b * (CAP * NBINS) + row * OWw;

    // Issue all 16 chunk loads up front (deep vmcnt pipeline; L2-resident
    // after the first of a batch's 60 blocks touches them).
    int vs[CH];
#pragma unroll
    for (int c = 0; c < CH; ++c) vs[c] = sp[c * 64 + lane];

    short* const slot_ok_base = &stage[wv][0][lane];     // + count*128 B
    short* const slot_dummy   = &stage[wv][WSLOTS][lane];

    int count = 0;
#pragma unroll
    for (int c = 0; c < CH; ++c) {
        const int v   = vs[c];
        const int khj = ((v >> 6) & 63) - row;
        const bool halo = (unsigned)khj < 5u;
        // Payload pre-pack (VALU, all lanes in parallel; garbage if !halo,
        // but non-halo lanes are never readlane'd).
        const int P = (((v >> 12) * 25 + khj * 5) << 6) | (v & 63);

        unsigned long long mask = __ballot(halo);      // wave-uniform (SGPR pair)
        while (mask) {                                  // uniform control flow
            const int j = (int)__builtin_ctzll(mask);   // s_ff1: lowest lane = earliest s
            mask &= mask - 1;
            const int Pj =
                __builtin_amdgcn_readlane(P, __builtin_amdgcn_readfirstlane(j));
            const int wj   = Pj & 63;                   // scalar extract
            const int sval = Pj >> 6;                   // scalar extract
            const int kw   = wj - lane;                 // per-lane
            const bool inwin = ((unsigned)kw < 5u) & valid;  // <=5 lanes
            // Branchless staged write: real slot or dummy row.
            short* a = (inwin & (count < WSLOTS))
                           ? (slot_ok_base + count * 64)  // short units: count*128 B
                           : slot_dummy;
            *a = (short)(sval + kw);                    // ckk (garbage to dummy ok)
            count += inwin;
        }
    }
    cnt[wv][lane] = count;
    if (__ballot(count > WSLOTS) && lane == 0) ovf = 1;  // benign multi-write
    __syncthreads();

    if (ovf == 0) {
        if (valid) {
            const int c0 = cnt[0][lane], c1 = cnt[1][lane];
            const int c2 = cnt[2][lane], c3 = cnt[3][lane];
            const int o1 = c0, o2 = c0 + c1, o3 = o2 + c2;
            const int total = o3 + c3;                 // <=192; write only k<128
#pragma unroll 4
            for (int i = 0; i < CAP / NW; ++i) {
                const int k = wv * (CAP / NW) + i;     // wave order == s order
                int val = -1;
                if (k < total) {
                    int wsel = 0, base = 0;
                    if (k >= o1) { wsel = 1; base = o1; }
                    if (k >= o2) { wsel = 2; base = o2; }
                    if (k >= o3) { wsel = 3; base = o3; }
                    val = (int)stage[wsel][k - base][lane];  // bank=lane>>1, free
                }
                outb[k * NBINS + lane] = val;          // contiguous 240 B run
            }
        }
    } else if (wv == 0) {
        // Fallback: >48 hits from one 1024-spike segment in one bin
        // (P ~ 1e-19 random input). Serial redo, direct global stores.
        const int* __restrict__ spf = spikes + b * NS;
        int cc = 0;
        for (int c = 0; c < NS / 64; ++c) {
            const int v = spf[c * 64 + lane];
            const int h = (v >> 6) & 63;
            unsigned long long mask = __ballot((unsigned)(h - row) < 5u);
            while (mask) {
                const int j = (int)__builtin_ctzll(mask);
                mask &= mask - 1;
                const int vj =
                    __builtin_amdgcn_readlane(v, __builtin_amdgcn_readfirstlane(j));
                const int wj  = vj & 63;
                const int khj = ((vj >> 6) & 63) - row;
                const int cj  = vj >> 12;
                const int kw  = wj - lane;
                if (((unsigned)kw < 5u) & valid) {
                    if (cc < CAP)
                        outb[cc * NBINS + lane] = cj * 25 + khj * 5 + kw;
                    ++cc;
                }
            }
        }
        if (valid)
            for (int k = cc; k < CAP; ++k) outb[k * NBINS + lane] = -1;
    }
}

extern "C" void kernel_launch(void* const* d_in, const int* in_sizes, int n_in,
                              void* d_out, int out_size, void* d_ws, size_t ws_size,
                              hipStream_t stream) {
    const int* spikes = (const int*)d_in[0];  // (B, S, 1, 1) int32
    // d_in[1] (indices table) unused: membership is pure arithmetic.
    int* out = (int*)d_out;                   // (B, CAP, OH, OW) int32

    dim3 grid(OHh * NB);                      // 3840 blocks, batch-minor
    dim3 block(256);                          // 4 waves/block
    sort_spikes_row4<<<grid, block, 0, stream>>>(spikes, out);
}

// Round 7
// 149.565 us; speedup vs baseline: 2.7910x; 1.0012x over previous
//
#include <hip/hip_runtime.h>

// Problem constants (fixed in the reference file)
#define OHh   60
#define OWw   60
#define NBINS (OHh * OWw)   // 3600
#define NB    64            // batches
#define NS    4096          // spikes per batch
#define CAP   128

#define NW     4            // waves per block
#define SEG    (NS / NW)    // 1024 spikes scanned per wave
#define CH     (SEG / 64)   // 16 chunks per wave
#define WSLOTS 40           // staged slots per wave-segment per bin (+1 dummy row)
                            // Poisson mean 6.25/bin/segment -> P(>40) ~ 1e-22

// One 4-wave block per (batch, output row); lane == ow (lanes 60..63 parked).
// R6 was scalar-unit-bound: ~8 SALU per broadcast-hit (s_ff1, 64b mask clear,
// extracts, loop ctrl) x 1.23M hits / 256 CUs ~= 16 us on the one shared
// SALU/CU. R7 removes ballot-iteration: halo lanes compact a 16-bit payload
// P = (w<<10)|(c*25+kh*5+w) into an LDS list at pos = mbcnt(mask) (lane order
// == s order), then a uniform for-loop broadcasts each hit with a same-address
// ds_read_u16 (conflict-free). Per hit: value = (P&0x3ff) - lane (ckk),
// window test = (P>>10) - lane_clamped < 5 -> ~10 VALU (4 SIMDs/CU) + ~3 SALU.
// Dump unchanged (WRITE_SIZE == output, ~1.0x amplification).
__global__ __launch_bounds__(256) void sort_spikes_row4(
    const int* __restrict__ spikes, int* __restrict__ out) {
    const int bid  = (int)blockIdx.x;
    const int b    = bid & (NB - 1);   // batch-minor -> batch b pinned to XCD b%8
    const int row  = bid >> 6;         // output row oh, 0..59
    const int tid  = (int)threadIdx.x;
    const int wv   = tid >> 6;
    const int lane = tid & 63;
    const bool valid  = lane < OWw;
    const int  lane_c = valid ? lane : 127;  // parked lanes: window test auto-fails

    __shared__ short          stage[NW][WSLOTS + 1][64];  // 20992 B (+1 = dummy sink row)
    __shared__ unsigned short hits[NW][64];               // compacted chunk payloads
    __shared__ int            cnt[NW][64];
    __shared__ int            ovf;

    if (tid == 0) ovf = 0;

    const int* __restrict__ sp   = spikes + b * NS + wv * SEG;
    int* __restrict__       outb = out + (size_t)b * (CAP * NBINS) + row * OWw;

    // Issue all 16 chunk loads up front (deep vmcnt pipeline; L2-resident
    // after the first of a batch's 60 blocks touches them).
    int vs[CH];
#pragma unroll
    for (int c = 0; c < CH; ++c) vs[c] = sp[c * 64 + lane];

    unsigned short* const hitbuf      = &hits[wv][0];
    short* const          stage_lane  = &stage[wv][0][lane];      // + count*64 shorts
    short* const          stage_dummy = &stage[wv][WSLOTS][lane]; // per-lane spread sink

    int count = 0;
#pragma unroll
    for (int c = 0; c < CH; ++c) {
        const int v   = vs[c];
        const int kh  = ((v >> 6) & 63) - row;
        const bool halo = (unsigned)kh < 5u;
        const int w   = v & 63;
        const int A   = (v >> 12) * 25 + kh * 5 + w;  // ckk_base + w, fits 10 bits
        const unsigned short P = (unsigned short)((w << 10) | A);

        const unsigned long long mask = __ballot(halo);   // wave-uniform
        const int pos = __builtin_amdgcn_mbcnt_hi(
            (unsigned)(mask >> 32),
            __builtin_amdgcn_mbcnt_lo((unsigned)mask, 0));  // rank among halo lanes
        if (halo) hitbuf[pos] = P;                          // s-order preserved
        const int n = __popcll(mask);                       // s_bcnt1, uniform

        for (int i = 0; i < n; ++i) {            // uniform trip count
            const int Pj  = (int)hitbuf[i];      // ds_read_u16 same-addr broadcast
            const int kw  = (Pj >> 10) - lane_c; // per-lane window offset
            const bool inwin = (unsigned)kw < 5u;
            const int val = (Pj & 0x3ff) - lane_c;           // == ckk when inwin
            short* a = (inwin & (count < WSLOTS))
                           ? (stage_lane + count * 64)       // count*128 B
                           : stage_dummy;
            *a = (short)val;                      // garbage to dummy sink is fine
            count += inwin;
        }
    }
    cnt[wv][lane] = count;
    if (__ballot(count > WSLOTS) && lane == 0) ovf = 1;  // benign multi-write
    __syncthreads();

    if (ovf == 0) {
        if (valid) {
            const int c0 = cnt[0][lane], c1 = cnt[1][lane];
            const int c2 = cnt[2][lane], c3 = cnt[3][lane];
            const int o1 = c0, o2 = c0 + c1, o3 = o2 + c2;
            const int total = o3 + c3;                 // <=160; write only k<128
#pragma unroll 4
            for (int i = 0; i < CAP / NW; ++i) {
                const int k = wv * (CAP / NW) + i;     // wave order == s order
                int val = -1;
                if (k < total) {
                    int wsel = 0, base = 0;
                    if (k >= o1) { wsel = 1; base = o1; }
                    if (k >= o2) { wsel = 2; base = o2; }
                    if (k >= o3) { wsel = 3; base = o3; }
                    val = (int)stage[wsel][k - base][lane];  // bank=lane>>1, free
                }
                outb[k * NBINS + lane] = val;          // contiguous 240 B run
            }
        }
    } else if (wv == 0) {
        // Fallback: >40 staged hits from one 1024-spike segment in one bin
        // (P ~ 1e-22 random input). Serial redo, direct global stores.
        const int* __restrict__ spf = spikes + b * NS;
        int cc = 0;
        for (int c = 0; c < NS / 64; ++c) {
            const int v = spf[c * 64 + lane];
            const int h = (v >> 6) & 63;
            unsigned long long mask = __ballot((unsigned)(h - row) < 5u);
            while (mask) {
                const int j = (int)__builtin_ctzll(mask);
                mask &= mask - 1;
                const int vj =
                    __builtin_amdgcn_readlane(v, __builtin_amdgcn_readfirstlane(j));
                const int wj  = vj & 63;
                const int khj = ((vj >> 6) & 63) - row;
                const int cj  = vj >> 12;
                const int kw  = wj - lane;
                if (((unsigned)kw < 5u) & valid) {
                    if (cc < CAP)
                        outb[cc * NBINS + lane] = cj * 25 + khj * 5 + kw;
                    ++cc;
                }
            }
        }
        if (valid)
            for (int k = cc; k < CAP; ++k) outb[k * NBINS + lane] = -1;
    }
}

extern "C" void kernel_launch(void* const* d_in, const int* in_sizes, int n_in,
                              void* d_out, int out_size, void* d_ws, size_t ws_size,
                              hipStream_t stream) {
    const int* spikes = (const int*)d_in[0];  // (B, S, 1, 1) int32
    // d_in[1] (indices table) unused: membership is pure arithmetic.
    int* out = (int*)d_out;                   // (B, CAP, OH, OW) int32

    dim3 grid(OHh * NB);                      // 3840 blocks, batch-minor
    dim3 block(256);                          // 4 waves/block
    sort_spikes_row4<<<grid, block, 0, stream>>>(spikes, out);
}

// Round 8
// 147.170 us; speedup vs baseline: 2.8364x; 1.0163x over previous
//
#include <hip/hip_runtime.h>

// Problem constants (fixed in the reference file)
#define OHh   60
#define OWw   60
#define NBINS (OHh * OWw)   // 3600
#define NB    64            // batches
#define NS    4096          // spikes per batch
#define CAP   128

#define NW     4            // waves per block
#define SEG    (NS / NW)    // 1024 spikes scanned per wave
#define CH     (SEG / 64)   // 16 chunks per wave
#define WSLOTS 40           // staged slots per wave-segment per bin (+1 dummy row)
#define PRE0   64           // slots [PRE0, CAP) prefilled -1 during scan
                            // (per-bin total ~ Poisson(25); P(>64) ~ 1e-11)

// One 4-wave block per (batch, output row); lane == ow (lanes 60..63 parked).
// R7 post-mortem: scan (~25 us, LDS-pipe/SALU bound) and dump (~19 us, at the
// ~6.7 TB/s write ceiling) are serialized by __syncthreads. R8 overlaps them:
// slots [64,128) are -1 w.p. 1-1e-11, so each wave streams one 240 B -1
// row-store per chunk during the scan (64 slots total, ~59 MB hidden under
// the scan at 2.4 TB/s), and the post-barrier dump shrinks to slots [0,64).
// Store pattern is the proven contiguous-240B-run layout (WRITE_SIZE ~= 1.0x
// output). A per-lane guarded loop covers the never-taken total>64 case.
__global__ __launch_bounds__(256) void sort_spikes_row4(
    const int* __restrict__ spikes, int* __restrict__ out) {
    const int bid  = (int)blockIdx.x;
    const int b    = bid & (NB - 1);   // batch-minor -> batch b pinned to XCD b%8
    const int row  = bid >> 6;         // output row oh, 0..59
    const int tid  = (int)threadIdx.x;
    const int wv   = tid >> 6;
    const int lane = tid & 63;
    const bool valid  = lane < OWw;
    const int  lane_c = valid ? lane : 127;  // parked lanes: window test auto-fails

    __shared__ short          stage[NW][WSLOTS + 1][64];  // 20992 B (+1 dummy sink)
    __shared__ unsigned short hits[NW][64];               // compacted chunk payloads
    __shared__ int            cnt[NW][64];
    __shared__ int            ovf;

    if (tid == 0) ovf = 0;

    const int* __restrict__ sp   = spikes + b * NS + wv * SEG;
    int* __restrict__       outb = out + (size_t)b * (CAP * NBINS) + row * OWw;

    // Issue all 16 chunk loads up front (deep vmcnt pipeline; L2-resident
    // after the first of a batch's 60 blocks touches them).
    int vs[CH];
#pragma unroll
    for (int c = 0; c < CH; ++c) vs[c] = sp[c * 64 + lane];

    unsigned short* const hitbuf      = &hits[wv][0];
    short* const          stage_lane  = &stage[wv][0][lane];      // + count*64 shorts
    short* const          stage_dummy = &stage[wv][WSLOTS][lane]; // sink row

    int count = 0;
#pragma unroll
    for (int c = 0; c < CH; ++c) {
        const int v   = vs[c];
        const int kh  = ((v >> 6) & 63) - row;
        const bool halo = (unsigned)kh < 5u;
        const int w   = v & 63;
        const int A   = (v >> 12) * 25 + kh * 5 + w;  // ckk_base + w, fits 10 bits
        const unsigned short P = (unsigned short)((w << 10) | A);

        const unsigned long long mask = __ballot(halo);   // wave-uniform
        const int pos = __builtin_amdgcn_mbcnt_hi(
            (unsigned)(mask >> 32),
            __builtin_amdgcn_mbcnt_lo((unsigned)mask, 0));  // rank among halo lanes
        if (halo) hitbuf[pos] = P;                          // s-order preserved
        const int n = __popcll(mask);                       // uniform

        for (int i = 0; i < n; ++i) {            // uniform trip count
            const int Pj  = (int)hitbuf[i];      // ds_read_u16 same-addr broadcast
            const int kw  = (Pj >> 10) - lane_c; // per-lane window offset
            const bool inwin = (unsigned)kw < 5u;
            const int val = (Pj & 0x3ff) - lane_c;           // == ckk when inwin
            short* a = (inwin & (count < WSLOTS))
                           ? (stage_lane + count * 64)       // count*128 B
                           : stage_dummy;
            *a = (short)val;                      // garbage to sink is fine
            count += inwin;
        }

        // Hidden write: one -1 slot-row per chunk -> slots [64,128) done by
        // scan end (wv*CH+c spans 0..63). Contiguous 240 B run, paced at
        // ~2.4 TB/s under the scan.
        if (valid) outb[(PRE0 + wv * CH + c) * NBINS + lane] = -1;
    }
    cnt[wv][lane] = count;
    if (__ballot(count > WSLOTS) && lane == 0) ovf = 1;  // benign multi-write
    __syncthreads();

    if (ovf == 0) {
        if (valid) {
            const int c0 = cnt[0][lane], c1 = cnt[1][lane];
            const int c2 = cnt[2][lane], c3 = cnt[3][lane];
            const int o1 = c0, o2 = c0 + c1, o3 = o2 + c2;
            const int total = o3 + c3;                 // <=160
            // Dump slots [0,64): 16 per wave, wave order == s order.
#pragma unroll 4
            for (int i = 0; i < PRE0 / NW; ++i) {
                const int k = wv * (PRE0 / NW) + i;
                int val = -1;
                if (k < total) {
                    int wsel = 0, base = 0;
                    if (k >= o1) { wsel = 1; base = o1; }
                    if (k >= o2) { wsel = 2; base = o2; }
                    if (k >= o3) { wsel = 3; base = o3; }
                    val = (int)stage[wsel][k - base][lane];  // bank=lane>>1, free
                }
                outb[k * NBINS + lane] = val;          // contiguous 240 B run
            }
            // Astronomically rare: overwrite prefilled -1s with real values.
            for (int k = PRE0 + wv; k < total && k < CAP; k += NW) {
                int wsel = 0, base = 0;
                if (k >= o1) { wsel = 1; base = o1; }
                if (k >= o2) { wsel = 2; base = o2; }
                if (k >= o3) { wsel = 3; base = o3; }
                outb[k * NBINS + lane] = (int)stage[wsel][k - base][lane];
            }
        }
    } else if (wv == 0) {
        // Fallback: >40 staged hits in one bin from one 1024-spike segment
        // (P ~ 1e-22 random input). Serial redo, direct global stores.
        const int* __restrict__ spf = spikes + b * NS;
        int cc = 0;
        for (int c = 0; c < NS / 64; ++c) {
            const int v = spf[c * 64 + lane];
            const int h = (v >> 6) & 63;
            unsigned long long mask = __ballot((unsigned)(h - row) < 5u);
            while (mask) {
                const int j = (int)__builtin_ctzll(mask);
                mask &= mask - 1;
                const int vj =
                    __builtin_amdgcn_readlane(v, __builtin_amdgcn_readfirstlane(j));
                const int wj  = vj & 63;
                const int khj = ((vj >> 6) & 63) - row;
                const int cj  = vj >> 12;
                const int kw  = wj - lane;
                if (((unsigned)kw < 5u) & valid) {
                    if (cc < CAP)
                        outb[cc * NBINS + lane] = cj * 25 + khj * 5 + kw;
                    ++cc;
                }
            }
        }
        if (valid)
            for (int k = cc; k < CAP; ++k) outb[k * NBINS + lane] = -1;
    }
}

extern "C" void kernel_launch(void* const* d_in, const int* in_sizes, int n_in,
                              void* d_out, int out_size, void* d_ws, size_t ws_size,
                              hipStream_t stream) {
    const int* spikes = (const int*)d_in[0];  // (B, S, 1, 1) int32
    // d_in[1] (indices table) unused: membership is pure arithmetic.
    int* out = (int*)d_out;                   // (B, CAP, OH, OW) int32

    dim3 grid(OHh * NB);                      // 3840 blocks, batch-minor
    dim3 block(256);                          // 4 waves/block
    sort_spikes_row4<<<grid, block, 0, stream>>>(spikes, out);
}